// Round 11
// baseline (38.366 us; speedup 1.0000x reference)
//
#include <hip/hip_runtime.h>
#include <hip/hip_bf16.h>
#include <stdint.h>

// Problem constants (from reference)
#define N_SAMP 16384
#define DCONT  64
#define DCAT   2000
#define EMB    64
#define BM 16                   // rows per block
#define NT_TOT 66               // 64 cat K-steps of 32 (permuted) + 2 cont steps

typedef short bf16x8 __attribute__((ext_vector_type(8)));
typedef float f32x4  __attribute__((ext_vector_type(4)));

__device__ __forceinline__ uint16_t f2bf(float f) {
    union { float f; uint32_t u; } v; v.f = f;
    uint32_t r = v.u + 0x7FFFu + ((v.u >> 16) & 1u);   // RNE
    return (uint16_t)(r >> 16);
}
__device__ __forceinline__ uint32_t pack2f(float a, float b) {
    return (uint32_t)f2bf(a) | ((uint32_t)f2bf(b) << 16);
}

// Build B in MFMA FRAGMENT ORDER: BF[t][n][lane] = 8 bf16 (16 B).
// Step t, col-frag n, lane (g=lane>>4, lr=lane&15) holds col c=n*16+lr,
// permuted-k p = t*32 + g*8 + j (j=0..7).
//   p < 2048 : cat. Bit b of mask word W (p=32W+b) maps to
//              kc = 256*(W>>3) + 128*(W&1) + 4*b + ((W>>1)&3)  [validated R8-R10]
//   p >= 2048: W_cont[p-2048][c]
__global__ void build_bfrag_kernel(const float* __restrict__ Wcont,
                                   const float* __restrict__ Wcat,
                                   uint16_t* __restrict__ BF) {
    const int t = blockIdx.x, n = blockIdx.y;
    const int lane = threadIdx.x;
    const int g = lane >> 4, lr = lane & 15;
    const int c = n * 16 + lr;
    uint16_t vals[8];
    #pragma unroll
    for (int j = 0; j < 8; ++j) {
        const int p = t * 32 + g * 8 + j;
        float v = 0.f;
        if (p < 2048) {
            const int W = p >> 5, b = p & 31;
            const int kc = 256 * (W >> 3) + 128 * (W & 1) + 4 * b + ((W >> 1) & 3);
            if (kc < DCAT) v = Wcat[(long)kc * EMB + c];
        } else {
            v = Wcont[(long)(p - 2048) * EMB + c];
        }
        vals[j] = f2bf(v);
    }
    *(int4*)(BF + ((long)(t * 4 + n) * 64 + lane) * 8) = *(const int4*)vals;
}

struct BFrag { bf16x8 b0, b1, b2, b3; };       // 4 col-frags, contiguous 4KB in BF

__global__ __launch_bounds__(256, 4)
void fm_fused(const float* __restrict__ xc,
              const int*   __restrict__ xcat,
              const uint16_t* __restrict__ BF,
              float* __restrict__ out) {
    // BM=16 rows/block, 1024 blocks -> 4 blocks/CU, 16 waves/CU for streaming.
    // Phase 1: each wave compresses 4 rows of xcat (coalesced int4 + ballot)
    //          into LDS bitmask [16][68]  (bit-permutation validated R8-R10).
    // Phase 2: bitmask MFMA; each wave = K-quarter of the same 16 rows;
    //          B loads are contiguous 1KB fragment reads (L2-hot).
    __shared__ uint32_t smem[4 * BM * EMB];    // 16 KB (mask overlay, then part)

    const int tid  = threadIdx.x;
    const int w    = tid >> 6;
    const int lane = tid & 63;
    const int g    = lane >> 4;
    const int lr   = lane & 15;
    const int r0   = blockIdx.x * BM;

    // ---- Phase 1: compress 16 rows -> LDS masks
    #pragma unroll 1
    for (int rr = 0; rr < 4; ++rr) {
        const int row = w * 4 + rr;                       // 0..15 in block
        const int* rp = xcat + (long)(r0 + row) * DCAT + lane * 4;
        uint32_t word = 0;
        #pragma unroll
        for (int i = 0; i < 8; ++i) {
            int4 v = make_int4(0, 0, 0, 0);
            if (i < 7 || lane < 52)                       // k>=2000 -> 0
                v = *(const int4*)(rp + i * 256);         // contiguous 1KB/wave
            unsigned long long b0 = __ballot(v.x != 0);
            unsigned long long b1 = __ballot(v.y != 0);
            unsigned long long b2 = __ballot(v.z != 0);
            unsigned long long b3 = __ballot(v.w != 0);
            unsigned long long t0 = ((lane >> 1) & 1) ? b1 : b0;
            unsigned long long t1 = ((lane >> 1) & 1) ? b3 : b2;
            unsigned long long t  = ((lane >> 2) & 1) ? t1 : t0;
            uint32_t val = (lane & 1) ? (uint32_t)(t >> 32) : (uint32_t)t;
            word = (i == (lane >> 3)) ? val : word;       // lane L ends with word L
        }
        smem[row * 68 + lane] = word;
    }
    __syncthreads();

    // ---- this wave's mask slice: words w*16..+16 of row lr
    int4 m0[4];
    #pragma unroll
    for (int q = 0; q < 4; ++q)
        m0[q] = *(const int4*)&smem[lr * 68 + w * 16 + q * 4];
    __syncthreads();                                      // masks dead; smem -> part

    f32x4 acc[4] = { {0,0,0,0}, {0,0,0,0}, {0,0,0,0}, {0,0,0,0} };

    auto loadBF = [&](int t) -> BFrag {
        const uint16_t* base = BF + (long)t * 2048 + lane * 8;   // frag-ordered
        BFrag f;
        f.b0 = *(const bf16x8*)(base);                            // 1KB contiguous
        f.b1 = *(const bf16x8*)(base + 512);
        f.b2 = *(const bf16x8*)(base + 1024);
        f.b3 = *(const bf16x8*)(base + 1536);
        return f;
    };
    // expand 8 bits (byte g of word) -> 8 bf16 {0,1}
    auto expand = [&](uint32_t word) -> bf16x8 {
        const uint32_t b = (word >> (g * 8)) & 0xFFu;
        union { uint32_t u[4]; bf16x8 v; } cv;
        #pragma unroll
        for (int j = 0; j < 4; ++j) {
            const uint32_t b0 = (b >> (2 * j)) & 1u;
            const uint32_t b1 = (b >> (2 * j + 1)) & 1u;
            cv.u[j] = (b0 + (b1 << 16)) * 0x3F80u;
        }
        return cv.v;
    };
    auto mmac = [&](bf16x8 af, const BFrag& B) {
        acc[0] = __builtin_amdgcn_mfma_f32_16x16x32_bf16(af, B.b0, acc[0], 0, 0, 0);
        acc[1] = __builtin_amdgcn_mfma_f32_16x16x32_bf16(af, B.b1, acc[1], 0, 0, 0);
        acc[2] = __builtin_amdgcn_mfma_f32_16x16x32_bf16(af, B.b2, acc[2], 0, 0, 0);
        acc[3] = __builtin_amdgcn_mfma_f32_16x16x32_bf16(af, B.b3, acc[3], 0, 0, 0);
    };

    // ---- main loop: 16 K-steps; B 2-deep register pipeline; no barriers
    const int t0i = w * 16;
    BFrag bb0 = loadBF(t0i), bb1 = loadBF(t0i + 1);
    #pragma unroll
    for (int s = 0; s < 16; ++s) {
        const int q = s >> 2, r = s & 3;
        uint32_t w0;
        w0 = (r == 0) ? m0[q].x : (r == 1) ? m0[q].y : (r == 2) ? m0[q].z : m0[q].w;
        bf16x8 af = expand(w0);
        __builtin_amdgcn_sched_barrier(0);
        if (s & 1) { mmac(af, bb1); if (s + 2 < 16) bb1 = loadBF(t0i + s + 2); }
        else       { mmac(af, bb0); if (s + 2 < 16) bb0 = loadBF(t0i + s + 2); }
        __builtin_amdgcn_sched_barrier(0);
    }

    // ---- continuous part: waves 2,3 take steps t=64,65
    if (w >= 2) {
        const int cs = w - 2;
        const float* xP0 = xc + (long)(r0 + lr) * DCONT + cs * 32 + g * 8;
        float4 x0 = *(const float4*)(xP0);
        float4 x1 = *(const float4*)(xP0 + 4);
        BFrag bc = loadBF(64 + cs);
        union { uint32_t u[4]; bf16x8 v; } c0;
        c0.u[0] = pack2f(x0.x, x0.y); c0.u[1] = pack2f(x0.z, x0.w);
        c0.u[2] = pack2f(x1.x, x1.y); c0.u[3] = pack2f(x1.z, x1.w);
        mmac(c0.v, bc);
    }

    // ---- epilogue: combine 4 wave-partials; out[r] = 0.5*||s_row||^2
    // lane (g,lr): rows g*4+r, col n*16+lr
    #pragma unroll
    for (int n = 0; n < 4; ++n)
        #pragma unroll
        for (int r = 0; r < 4; ++r)
            ((float*)smem)[(w * BM + g * 4 + r) * EMB + n * 16 + lr] = acc[n][r];
    __syncthreads();

    const int row = tid >> 4;           // 0..15
    const int c0i = (tid & 15) * 4;     // 4 cols per thread
    float4 v0 = *(const float4*)&((float*)smem)[(0 * BM + row) * EMB + c0i];
    float4 v1 = *(const float4*)&((float*)smem)[(1 * BM + row) * EMB + c0i];
    float4 v2 = *(const float4*)&((float*)smem)[(2 * BM + row) * EMB + c0i];
    float4 v3 = *(const float4*)&((float*)smem)[(3 * BM + row) * EMB + c0i];
    float sx = v0.x + v1.x + v2.x + v3.x;
    float sy = v0.y + v1.y + v2.y + v3.y;
    float sz = v0.z + v1.z + v2.z + v3.z;
    float sw_ = v0.w + v1.w + v2.w + v3.w;
    float p = sx * sx + sy * sy + sz * sz + sw_ * sw_;
    p += __shfl_xor(p, 1);
    p += __shfl_xor(p, 2);
    p += __shfl_xor(p, 4);
    p += __shfl_xor(p, 8);
    if ((tid & 15) == 0) out[r0 + row] = 0.5f * p;
}

extern "C" void kernel_launch(void* const* d_in, const int* in_sizes, int n_in,
                              void* d_out, int out_size, void* d_ws, size_t ws_size,
                              hipStream_t stream) {
    const float* xc    = (const float*)d_in[0];   // data_continuous [N,64] f32
    const int*   xcat  = (const int*)d_in[1];     // data_category   [N,2000] i32
    const float* Wcont = (const float*)d_in[2];   // [64,64] f32
    const float* Wcat  = (const float*)d_in[3];   // [2000,64] f32
    uint16_t* BF = (uint16_t*)d_ws;               // fragment-ordered B: 66*4*64*16B = 270 KiB
    float* outp = (float*)d_out;

    build_bfrag_kernel<<<dim3(NT_TOT, 4), 64, 0, stream>>>(Wcont, Wcat, BF);
    fm_fused<<<N_SAMP / BM, 256, 0, stream>>>(xc, xcat, BF, outp);
}

// Round 12
// 35.440 us; speedup vs baseline: 1.0826x; 1.0826x over previous
//
#include <hip/hip_runtime.h>
#include <hip/hip_bf16.h>
#include <stdint.h>

// Problem constants (from reference)
#define N_SAMP 16384
#define DCONT  64
#define DCAT   2000
#define EMB    64
#define BM 32                   // rows per block
#define NT_TOT 66               // 64 cat K-steps of 32 (permuted) + 2 cont steps

typedef short bf16x8 __attribute__((ext_vector_type(8)));
typedef float f32x4  __attribute__((ext_vector_type(4)));
typedef unsigned long long ull;

__device__ __forceinline__ uint16_t f2bf(float f) {
    union { float f; uint32_t u; } v; v.f = f;
    uint32_t r = v.u + 0x7FFFu + ((v.u >> 16) & 1u);   // RNE
    return (uint16_t)(r >> 16);
}
__device__ __forceinline__ uint32_t pack2f(float a, float b) {
    return (uint32_t)f2bf(a) | ((uint32_t)f2bf(b) << 16);
}

// Build B in MFMA FRAGMENT ORDER: BF[t][n][lane] = 8 bf16 (16 B).
// Step t, col-frag n, lane (g=lane>>4, lr=lane&15) holds col c=n*16+lr,
// permuted-k p = t*32 + g*8 + j (j=0..7).
//   p < 2048 : cat. Bit b of mask word W (p=32W+b) maps to
//              kc = 256*(W>>3) + 128*(W&1) + 4*b + ((W>>1)&3)  [validated R8-R11]
//   p >= 2048: W_cont[p-2048][c]
__global__ void build_bfrag_kernel(const float* __restrict__ Wcont,
                                   const float* __restrict__ Wcat,
                                   uint16_t* __restrict__ BF) {
    const int t = blockIdx.x, n = blockIdx.y;
    const int lane = threadIdx.x;
    const int g = lane >> 4, lr = lane & 15;
    const int c = n * 16 + lr;
    uint16_t vals[8];
    #pragma unroll
    for (int j = 0; j < 8; ++j) {
        const int p = t * 32 + g * 8 + j;
        float v = 0.f;
        if (p < 2048) {
            const int W = p >> 5, b = p & 31;
            const int kc = 256 * (W >> 3) + 128 * (W & 1) + 4 * b + ((W >> 1) & 3);
            if (kc < DCAT) v = Wcat[(long)kc * EMB + c];
        } else {
            v = Wcont[(long)(p - 2048) * EMB + c];
        }
        vals[j] = f2bf(v);
    }
    *(int4*)(BF + ((long)(t * 4 + n) * 64 + lane) * 8) = *(const int4*)vals;
}

struct BFrag { bf16x8 b0, b1, b2, b3; };       // 4 col-frags, contiguous 4KB in BF

__global__ __launch_bounds__(256, 2)
void fm_fused(const float* __restrict__ xc,
              const int*   __restrict__ xcat,
              const uint16_t* __restrict__ BF,
              float* __restrict__ out) {
    // Wave-independent structure: wave w compresses xcat cols [512w, 512w+512)
    // (= mask words [16w,16w+16)) of ALL 32 rows into its PRIVATE LDS strip,
    // then immediately runs its K-quarter MFMA. No barrier between stream and
    // compute; only the final cross-wave reduction syncs.
    __shared__ uint32_t maskL[4][BM][17];      // 8.5 KB, per-wave strips
    __shared__ float    part[4][BM][EMB];      // 32 KB

    const int tid  = threadIdx.x;
    const int w    = tid >> 6;
    const int lane = tid & 63;
    const int g    = lane >> 4;
    const int lr   = lane & 15;
    const int r0   = blockIdx.x * BM;

    // ---- Phase 1 (wave-private): compress chunk pair {2w, 2w+1} of 32 rows
    const int* bp = xcat + (long)r0 * DCAT + 512 * w + lane * 4;
    #pragma unroll 1
    for (int r4 = 0; r4 < BM; r4 += 4) {
        int4 va[4], vb[4];
        #pragma unroll
        for (int rr = 0; rr < 4; ++rr) {
            const int* rp = bp + (long)(r4 + rr) * DCAT;
            va[rr] = *(const int4*)(rp);
            vb[rr] = (w < 3 || lane < 52) ? *(const int4*)(rp + 256)
                                          : make_int4(0, 0, 0, 0);
        }
        #pragma unroll
        for (int rr = 0; rr < 4; ++rr) {
            ull a0 = __ballot(va[rr].x != 0), a1 = __ballot(va[rr].y != 0);
            ull a2 = __ballot(va[rr].z != 0), a3 = __ballot(va[rr].w != 0);
            ull c0 = __ballot(vb[rr].x != 0), c1 = __ballot(vb[rr].y != 0);
            ull c2 = __ballot(vb[rr].z != 0), c3 = __ballot(vb[rr].w != 0);
            // every lane computes word 16w + (lane&15); lanes 0..15 store strip
            ull s0 = (lane & 8) ? c0 : a0;
            ull s1 = (lane & 8) ? c1 : a1;
            ull s2 = (lane & 8) ? c2 : a2;
            ull s3 = (lane & 8) ? c3 : a3;
            ull t0 = (lane & 2) ? s1 : s0;
            ull t1 = (lane & 2) ? s3 : s2;
            ull t  = (lane & 4) ? t1 : t0;
            uint32_t val = (lane & 1) ? (uint32_t)(t >> 32) : (uint32_t)t;
            if (lane < 16) maskL[w][r4 + rr][lane] = val;
        }
    }

    // ---- this wave's mask regs (same-wave producer: lgkmcnt only, no barrier)
    int4 m0[4], m1[4];
    #pragma unroll
    for (int q = 0; q < 4; ++q) {
        m0[q] = *(const int4*)&maskL[w][lr][4 * q];
        m1[q] = *(const int4*)&maskL[w][16 + lr][4 * q];
    }

    f32x4 acc[2][4] = { { {0,0,0,0},{0,0,0,0},{0,0,0,0},{0,0,0,0} },
                        { {0,0,0,0},{0,0,0,0},{0,0,0,0},{0,0,0,0} } };

    auto loadBF = [&](int t) -> BFrag {
        const uint16_t* base = BF + (long)t * 2048 + lane * 8;   // frag-ordered
        BFrag f;
        f.b0 = *(const bf16x8*)(base);                            // 1KB contiguous
        f.b1 = *(const bf16x8*)(base + 512);
        f.b2 = *(const bf16x8*)(base + 1024);
        f.b3 = *(const bf16x8*)(base + 1536);
        return f;
    };
    auto expand = [&](uint32_t word) -> bf16x8 {
        const uint32_t b = (word >> (g * 8)) & 0xFFu;
        union { uint32_t u[4]; bf16x8 v; } cv;
        #pragma unroll
        for (int j = 0; j < 4; ++j) {
            const uint32_t b0 = (b >> (2 * j)) & 1u;
            const uint32_t b1 = (b >> (2 * j + 1)) & 1u;
            cv.u[j] = (b0 + (b1 << 16)) * 0x3F80u;
        }
        return cv.v;
    };
    auto mmac = [&](bf16x8 af0, bf16x8 af1, const BFrag& B) {
        acc[0][0] = __builtin_amdgcn_mfma_f32_16x16x32_bf16(af0, B.b0, acc[0][0], 0, 0, 0);
        acc[0][1] = __builtin_amdgcn_mfma_f32_16x16x32_bf16(af0, B.b1, acc[0][1], 0, 0, 0);
        acc[0][2] = __builtin_amdgcn_mfma_f32_16x16x32_bf16(af0, B.b2, acc[0][2], 0, 0, 0);
        acc[0][3] = __builtin_amdgcn_mfma_f32_16x16x32_bf16(af0, B.b3, acc[0][3], 0, 0, 0);
        acc[1][0] = __builtin_amdgcn_mfma_f32_16x16x32_bf16(af1, B.b0, acc[1][0], 0, 0, 0);
        acc[1][1] = __builtin_amdgcn_mfma_f32_16x16x32_bf16(af1, B.b1, acc[1][1], 0, 0, 0);
        acc[1][2] = __builtin_amdgcn_mfma_f32_16x16x32_bf16(af1, B.b2, acc[1][2], 0, 0, 0);
        acc[1][3] = __builtin_amdgcn_mfma_f32_16x16x32_bf16(af1, B.b3, acc[1][3], 0, 0, 0);
    };

    // ---- main loop: 16 K-steps; B 2-deep register pipeline; no barriers
    const int t0i = w * 16;
    BFrag bb0 = loadBF(t0i), bb1 = loadBF(t0i + 1);
    #pragma unroll
    for (int s = 0; s < 16; ++s) {
        const int q = s >> 2, r = s & 3;
        uint32_t w0, w1;
        w0 = (r == 0) ? m0[q].x : (r == 1) ? m0[q].y : (r == 2) ? m0[q].z : m0[q].w;
        w1 = (r == 0) ? m1[q].x : (r == 1) ? m1[q].y : (r == 2) ? m1[q].z : m1[q].w;
        bf16x8 af0 = expand(w0);
        bf16x8 af1 = expand(w1);
        __builtin_amdgcn_sched_barrier(0);
        if (s & 1) { mmac(af0, af1, bb1); if (s + 2 < 16) bb1 = loadBF(t0i + s + 2); }
        else       { mmac(af0, af1, bb0); if (s + 2 < 16) bb0 = loadBF(t0i + s + 2); }
        __builtin_amdgcn_sched_barrier(0);
    }

    // ---- continuous part: waves 2,3 take steps t=64,65
    if (w >= 2) {
        const int cs = w - 2;
        const float* xP0 = xc + (long)(r0 + lr) * DCONT + cs * 32 + g * 8;
        const float* xP1 = xc + (long)(r0 + 16 + lr) * DCONT + cs * 32 + g * 8;
        float4 x0 = *(const float4*)(xP0);
        float4 x1 = *(const float4*)(xP0 + 4);
        float4 x2 = *(const float4*)(xP1);
        float4 x3 = *(const float4*)(xP1 + 4);
        BFrag bc = loadBF(64 + cs);
        union { uint32_t u[4]; bf16x8 v; } c0, c1;
        c0.u[0] = pack2f(x0.x, x0.y); c0.u[1] = pack2f(x0.z, x0.w);
        c0.u[2] = pack2f(x1.x, x1.y); c0.u[3] = pack2f(x1.z, x1.w);
        c1.u[0] = pack2f(x2.x, x2.y); c1.u[1] = pack2f(x2.z, x2.w);
        c1.u[2] = pack2f(x3.x, x3.y); c1.u[3] = pack2f(x3.z, x3.w);
        mmac(c0.v, c1.v, bc);
    }

    // ---- epilogue: combine 4 wave-partials; out[r] = 0.5*||s_row||^2
    // lane (g,lr): rows rf*16 + g*4 + r, col n*16 + lr
    #pragma unroll
    for (int rf = 0; rf < 2; ++rf)
        #pragma unroll
        for (int n = 0; n < 4; ++n)
            #pragma unroll
            for (int r = 0; r < 4; ++r)
                part[w][rf * 16 + g * 4 + r][n * 16 + lr] = acc[rf][n][r];
    __syncthreads();

    const int row = tid >> 3;           // 0..31
    const int c0i = (tid & 7) * 8;      // 8 cols per thread
    float p = 0.f;
    #pragma unroll
    for (int h = 0; h < 2; ++h) {
        float4 v0 = *(const float4*)&part[0][row][c0i + h * 4];
        float4 v1 = *(const float4*)&part[1][row][c0i + h * 4];
        float4 v2 = *(const float4*)&part[2][row][c0i + h * 4];
        float4 v3 = *(const float4*)&part[3][row][c0i + h * 4];
        float sx = v0.x + v1.x + v2.x + v3.x;
        float sy = v0.y + v1.y + v2.y + v3.y;
        float sz = v0.z + v1.z + v2.z + v3.z;
        float sw_ = v0.w + v1.w + v2.w + v3.w;
        p += sx * sx + sy * sy + sz * sz + sw_ * sw_;
    }
    p += __shfl_xor(p, 1);
    p += __shfl_xor(p, 2);
    p += __shfl_xor(p, 4);
    if ((tid & 7) == 0) out[r0 + row] = 0.5f * p;
}

extern "C" void kernel_launch(void* const* d_in, const int* in_sizes, int n_in,
                              void* d_out, int out_size, void* d_ws, size_t ws_size,
                              hipStream_t stream) {
    const float* xc    = (const float*)d_in[0];   // data_continuous [N,64] f32
    const int*   xcat  = (const int*)d_in[1];     // data_category   [N,2000] i32
    const float* Wcont = (const float*)d_in[2];   // [64,64] f32
    const float* Wcat  = (const float*)d_in[3];   // [2000,64] f32
    uint16_t* BF = (uint16_t*)d_ws;               // fragment-ordered B: 66*4*64*16B = 270 KiB
    float* outp = (float*)d_out;

    build_bfrag_kernel<<<dim3(NT_TOT, 4), 64, 0, stream>>>(Wcont, Wcat, BF);
    fm_fused<<<N_SAMP / BM, 256, 0, stream>>>(xc, xcat, BF, outp);
}